// Round 2
// baseline (431.635 us; speedup 1.0000x reference)
//
#include <hip/hip_runtime.h>
#include <hip/hip_cooperative_groups.h>
#include <math.h>

namespace cg = cooperative_groups;

#define SEQ 65536
#define FEAT 512
#define NCH 256
#define CHUNK 256
#define THRES1 0.8f
#define THRES_UP 0.5f
#define NEGINF -1e30f

// ---------------- K1: a = sigmoid(h @ W + b), one wave per row ----------------
__global__ __launch_bounds__(256) void k_matvec(const float* __restrict__ h,
                                                const float* __restrict__ W,
                                                const float* __restrict__ b,
                                                float* __restrict__ a) {
    int wave = threadIdx.x >> 6;
    int lane = threadIdx.x & 63;
    int row  = blockIdx.x * 4 + wave;
    const float4* hp = (const float4*)(h + (size_t)row * FEAT);
    const float4* wp = (const float4*)W;
    int base = lane * 2;  // each lane: elements [lane*8, lane*8+8)
    float4 h0 = hp[base], h1 = hp[base + 1];
    float4 w0 = wp[base], w1 = wp[base + 1];
    float s = h0.x * w0.x + h0.y * w0.y + h0.z * w0.z + h0.w * w0.w
            + h1.x * w1.x + h1.y * w1.y + h1.z * w1.z + h1.w * w1.w;
    #pragma unroll
    for (int off = 32; off; off >>= 1) s += __shfl_down(s, off, 64);
    if (lane == 0) a[row] = 1.0f / (1.0f + expf(-(s + b[0])));
}

__device__ __forceinline__ void affine_scan256(float* sc, float* sd, int t) {
    // callers must __syncthreads() after writing init values, before calling
    for (int d = 1; d < 256; d <<= 1) {
        float lc = 1.0f, ld = 0.0f;
        bool act = t >= d;
        if (act) { lc = sc[t - d]; ld = sd[t - d]; }
        __syncthreads();
        if (act) { sd[t] = sc[t] * ld + sd[t]; sc[t] = sc[t] * lc; }
        __syncthreads();
    }
}

// -------- K2 (cooperative): the entire scan pipeline in one kernel --------
// workspace float area sf_: lastm[256] Pch[256] Qch[256] Ech[256] Fch[256]
// workspace int   area si_: lastopen[256] lastgate[256] trigLast[256] fallLast[256]
__global__ __launch_bounds__(256) void k_scan(const float* __restrict__ u_pred,
                                              const float* __restrict__ label,
                                              const float* __restrict__ thres2,
                                              const float* __restrict__ a,
                                              float* __restrict__ out,
                                              float* __restrict__ sf_,
                                              int* __restrict__ si_) {
    cg::grid_group grid = cg::this_grid();
    __shared__ float sA[256], sB[256], sU[256];
    __shared__ int   iA[256], iB[256], iC[256];

    int t = threadIdx.x, c = blockIdx.x;
    int i = c * CHUNK + t;

    float* lastm = sf_;
    float* Pch   = sf_ + NCH;
    float* Qch   = sf_ + 2 * NCH;
    float* Ech   = sf_ + 3 * NCH;
    float* Fch   = sf_ + 4 * NCH;
    int* lastopen = si_;
    int* lastgate = si_ + NCH;
    int* trigLast = si_ + 2 * NCH;
    int* fallLast = si_ + 3 * NCH;

    // ---------- Phase 1: local scans over chunk c ----------
    float u   = u_pred[i];
    float lab = label[i];
    float a_i = a[i];
    sU[t] = u;
    __syncthreads();
    bool gate = u >= THRES_UP;
    bool gprevLocal = (t > 0) && (sU[t - 1] >= THRES_UP);
    bool gprev = (t > 0) ? gprevLocal : ((i > 0) && (u_pred[i - 1] >= THRES_UP));
    bool fall = gprev && !gate;
    bool trig = lab >= THRES1;

    sA[t] = gate ? u : NEGINF;                               // segmented run-max
    iA[t] = gate ? ((t > 0 && !gprevLocal) ? 1 : 0) : 1;     // boundary flag
    iB[t] = trig ? i : -1;                                   // last trigger idx
    iC[t] = fall ? i : -1;                                   // last fall idx
    __syncthreads();
    for (int d = 1; d < 256; d <<= 1) {
        float lm = NEGINF; int lr = 0, lt_ = -1, lf_ = -1;
        bool act = t >= d;
        if (act) { lm = sA[t - d]; lr = iA[t - d]; lt_ = iB[t - d]; lf_ = iC[t - d]; }
        __syncthreads();
        if (act) {
            if (!iA[t]) sA[t] = fmaxf(lm, sA[t]);
            iA[t] |= lr;
            iB[t] = max(iB[t], lt_);
            iC[t] = max(iC[t], lf_);
        }
        __syncthreads();
    }
    float m_loc = sA[t];
    int   open  = (iA[t] == 0 && gate) ? 1 : 0;
    int   lt    = iB[t];
    int   lfE   = (t == 0) ? -1 : iC[t - 1];
    if (t == 255) {
        lastm[c]    = sA[255];
        lastopen[c] = open;           // t==255's own open/gate
        lastgate[c] = gate ? 1 : 0;
        trigLast[c] = iB[255];
        fallLast[c] = iC[255];
    }
    if (c == 0 && t == 0) { out[4 * SEQ] = 0.0f; out[4 * SEQ + 1] = 0.0f; }
    __threadfence();
    grid.sync();

    // ---------- Phase 2: cross-chunk scan of summaries (redundant per block) ----------
    {
        bool lg = lastgate[t] != 0;
        sA[t] = lg ? lastm[t] : NEGINF;
        sB[t] = (lg && lastopen[t]) ? 0.0f : NEGINF;
        iA[t] = trigLast[t];
        iB[t] = fallLast[t];
    }
    __syncthreads();
    for (int d = 1; d < 256; d <<= 1) {
        float lA = NEGINF, lB = NEGINF; int lt_ = -1, lf_ = -1;
        bool act = t >= d;
        if (act) { lA = sA[t - d]; lB = sB[t - d]; lt_ = iA[t - d]; lf_ = iB[t - d]; }
        __syncthreads();
        if (act) {
            float nA = fmaxf(sA[t], sB[t] + lA);   // max-plus compose right∘left
            float nB = fmaxf(sB[t] + lB, NEGINF);
            sA[t] = nA; sB[t] = nB;
            iA[t] = max(iA[t], lt_);
            iB[t] = max(iB[t], lf_);
        }
        __syncthreads();
    }
    float inc_c; int trigIn_c, fallIn_c;
    if (c == 0) { inc_c = NEGINF; trigIn_c = -1; fallIn_c = -1; }
    else        { inc_c = sA[c - 1]; trigIn_c = iA[c - 1]; fallIn_c = iB[c - 1]; }
    __syncthreads();

    // ---------- Phase 3: finalize up_hat, local alpha affine scan ----------
    float uh = gate ? (open ? fmaxf(m_loc, inc_c) : m_loc) : u;
    out[3 * SEQ + i] = uh;   // up_hats
    out[2 * SEQ + i] = u;    // u_pred passthrough
    sA[t] = uh;
    sB[t] = (1.0f - uh) * a_i;
    __syncthreads();
    affine_scan256(sA, sB, t);
    float Pt = sA[t], Qt = sB[t];
    if (t == 255) { Pch[c] = Pt; Qch[c] = Qt; }
    __threadfence();
    grid.sync();

    // ---------- Phase 4: alpha incoming, finalize alpha, local y affine scan ----------
    sA[t] = Pch[t]; sB[t] = Qch[t];
    __syncthreads();
    affine_scan256(sA, sB, t);
    float alphaIn_c = (c == 0) ? 0.0f : sB[c - 1];
    __syncthreads();
    float al = Pt * alphaIn_c + Qt;
    out[SEQ + i] = al;  // alphas
    sA[t] = gate ? (1.0f - al) : 0.0f;
    sB[t] = gate ? al * uh : 0.0f;
    __syncthreads();
    affine_scan256(sA, sB, t);
    float Et = sA[t], Ft = sB[t];
    if (t == 255) { Ech[c] = Et; Fch[c] = Ft; }
    __threadfence();
    grid.sync();

    // ---------- Phase 5: y incoming, finalize y ----------
    sA[t] = Ech[t]; sB[t] = Fch[t];
    __syncthreads();
    affine_scan256(sA, sB, t);
    float yIn_c = (c == 0) ? 0.0f : sB[c - 1];
    float y_i = Et * yIn_c + Ft;
    out[i] = y_i;  // ys
    __threadfence();
    grid.sync();

    // ---------- Phase 6: loss/cnt at gate falling edges ----------
    float contrib = 0.0f;
    int flag = 0;
    if (fall) {
        int j  = max(lt, trigIn_c);    // last label-trigger <= i
        int pf = max(lfE, fallIn_c);   // last fall < i
        float lc = 0.0f;
        if (j > pf) {
            bool gj = u_pred[j] >= THRES_UP;
            float d = out[j] - label[j];
            lc = gj ? d * d : -1.0f;
        }
        bool isneg = (lc == -1.0f);
        bool nonzero = (lc != 0.0f);
        if (!isneg) {
            if (nonzero) { contrib = lc; flag = 1; }   // * R, R = 1.0
            else {
                float ypre = out[i - 1];
                if (ypre >= THRES1) {
                    float t2 = thres2[(i < 59) ? i : 59];
                    float d2 = ypre - t2;
                    contrib = d2 * d2; flag = 1;
                }
            }
        }
    }
    #pragma unroll
    for (int off = 32; off; off >>= 1) {
        contrib += __shfl_down(contrib, off, 64);
        flag    += __shfl_down(flag, off, 64);
    }
    if ((t & 63) == 0 && (contrib != 0.0f || flag != 0)) {
        atomicAdd(&out[4 * SEQ], contrib);
        atomicAdd(&out[4 * SEQ + 1], (float)flag);
    }
}

extern "C" void kernel_launch(void* const* d_in, const int* in_sizes, int n_in,
                              void* d_out, int out_size, void* d_ws, size_t ws_size,
                              hipStream_t stream) {
    const float* h      = (const float*)d_in[0];
    const float* W      = (const float*)d_in[1];
    const float* b      = (const float*)d_in[2];
    const float* u_pred = (const float*)d_in[4];
    const float* label  = (const float*)d_in[5];
    const float* thres2 = (const float*)d_in[6];
    float* out  = (float*)d_out;
    float* base = (float*)d_ws;

    float* a   = base;                       // SEQ floats
    float* sf_ = base + SEQ;                 // 5*NCH floats
    int*   si_ = (int*)(base + SEQ + 5 * NCH);  // 4*NCH ints

    k_matvec<<<SEQ / 4, 256, 0, stream>>>(h, W, b, a);

    void* args[] = { (void*)&u_pred, (void*)&label, (void*)&thres2, (void*)&a,
                     (void*)&out, (void*)&sf_, (void*)&si_ };
    hipLaunchCooperativeKernel((void*)k_scan, dim3(NCH), dim3(256), args, 0, stream);
}

// Round 3
// 345.849 us; speedup vs baseline: 1.2480x; 1.2480x over previous
//
#include <hip/hip_runtime.h>
#include <math.h>

#define SEQ 65536
#define FEAT 512
#define NCH 256
#define CHUNK 256
#define THRES1 0.8f
#define THRES_UP 0.5f
#define NEGINF -1e30f

// ---------------- K1: a = sigmoid(h @ W + b), one wave per row ----------------
// Also zeroes the grid-barrier counter for the following cooperative kernel.
__global__ __launch_bounds__(256) void k_matvec(const float* __restrict__ h,
                                                const float* __restrict__ W,
                                                const float* __restrict__ b,
                                                float* __restrict__ a,
                                                unsigned* __restrict__ cnt) {
    if (blockIdx.x == 0 && threadIdx.x == 0) *cnt = 0u;
    int wave = threadIdx.x >> 6;
    int lane = threadIdx.x & 63;
    int row  = blockIdx.x * 4 + wave;
    const float4* hp = (const float4*)(h + (size_t)row * FEAT);
    const float4* wp = (const float4*)W;
    int base = lane * 2;  // each lane: elements [lane*8, lane*8+8)
    float4 h0 = hp[base], h1 = hp[base + 1];
    float4 w0 = wp[base], w1 = wp[base + 1];
    float s = h0.x * w0.x + h0.y * w0.y + h0.z * w0.z + h0.w * w0.w
            + h1.x * w1.x + h1.y * w1.y + h1.z * w1.z + h1.w * w1.w;
    #pragma unroll
    for (int off = 32; off; off >>= 1) s += __shfl_down(s, off, 64);
    if (lane == 0) a[row] = 1.0f / (1.0f + expf(-(s + b[0])));
}

// Lightweight grid barrier: monotonic counter, one atomic per block.
// Requires all blocks co-resident (guaranteed by cooperative launch).
__device__ __forceinline__ void grid_barrier(unsigned* cnt, unsigned target, int t) {
    __syncthreads();
    if (t == 0) {
        __threadfence();  // device-scope release of all prior writes
        __hip_atomic_fetch_add(cnt, 1u, __ATOMIC_RELEASE, __HIP_MEMORY_SCOPE_AGENT);
        while (__hip_atomic_load(cnt, __ATOMIC_ACQUIRE, __HIP_MEMORY_SCOPE_AGENT) < target)
            __builtin_amdgcn_s_sleep(2);
        __threadfence();  // device-scope acquire before dependent reads
    }
    __syncthreads();
}

__device__ __forceinline__ void affine_scan256(float* sc, float* sd, int t) {
    // callers must __syncthreads() after writing init values, before calling
    for (int d = 1; d < 256; d <<= 1) {
        float lc = 1.0f, ld = 0.0f;
        bool act = t >= d;
        if (act) { lc = sc[t - d]; ld = sd[t - d]; }
        __syncthreads();
        if (act) { sd[t] = sc[t] * ld + sd[t]; sc[t] = sc[t] * lc; }
        __syncthreads();
    }
}

// -------- K2 (cooperative): the entire scan pipeline in one kernel --------
__global__ __launch_bounds__(256) void k_scan(const float* __restrict__ u_pred,
                                              const float* __restrict__ label,
                                              const float* __restrict__ thres2,
                                              const float* __restrict__ a,
                                              float* __restrict__ out,
                                              float* __restrict__ sf_,
                                              int* __restrict__ si_,
                                              unsigned* __restrict__ cnt) {
    __shared__ float sA[256], sB[256], sU[256];
    __shared__ int   iA[256], iB[256], iC[256];

    int t = threadIdx.x, c = blockIdx.x;
    int i = c * CHUNK + t;

    float* lastm = sf_;
    float* Pch   = sf_ + NCH;
    float* Qch   = sf_ + 2 * NCH;
    float* Ech   = sf_ + 3 * NCH;
    float* Fch   = sf_ + 4 * NCH;
    int* lastopen = si_;
    int* lastgate = si_ + NCH;
    int* trigLast = si_ + 2 * NCH;
    int* fallLast = si_ + 3 * NCH;

    // ---------- Phase 1: local scans over chunk c ----------
    float u   = u_pred[i];
    float lab = label[i];
    float a_i = a[i];
    sU[t] = u;
    __syncthreads();
    bool gate = u >= THRES_UP;
    bool gprevLocal = (t > 0) && (sU[t - 1] >= THRES_UP);
    bool gprev = (t > 0) ? gprevLocal : ((i > 0) && (u_pred[i - 1] >= THRES_UP));
    bool fall = gprev && !gate;
    bool trig = lab >= THRES1;

    sA[t] = gate ? u : NEGINF;                               // segmented run-max
    iA[t] = gate ? ((t > 0 && !gprevLocal) ? 1 : 0) : 1;     // boundary flag
    iB[t] = trig ? i : -1;                                   // last trigger idx
    iC[t] = fall ? i : -1;                                   // last fall idx
    __syncthreads();
    for (int d = 1; d < 256; d <<= 1) {
        float lm = NEGINF; int lr = 0, lt_ = -1, lf_ = -1;
        bool act = t >= d;
        if (act) { lm = sA[t - d]; lr = iA[t - d]; lt_ = iB[t - d]; lf_ = iC[t - d]; }
        __syncthreads();
        if (act) {
            if (!iA[t]) sA[t] = fmaxf(lm, sA[t]);
            iA[t] |= lr;
            iB[t] = max(iB[t], lt_);
            iC[t] = max(iC[t], lf_);
        }
        __syncthreads();
    }
    float m_loc = sA[t];
    int   open  = (iA[t] == 0 && gate) ? 1 : 0;
    int   lt    = iB[t];
    int   lfE   = (t == 0) ? -1 : iC[t - 1];
    if (t == 255) {
        lastm[c]    = sA[255];
        lastopen[c] = open;
        lastgate[c] = gate ? 1 : 0;
        trigLast[c] = iB[255];
        fallLast[c] = iC[255];
    }
    if (c == 0 && t == 0) { out[4 * SEQ] = 0.0f; out[4 * SEQ + 1] = 0.0f; }
    grid_barrier(cnt, 1 * NCH, t);

    // ---------- Phase 2: cross-chunk scan of summaries (redundant per block) ----------
    {
        bool lg = lastgate[t] != 0;
        sA[t] = lg ? lastm[t] : NEGINF;
        sB[t] = (lg && lastopen[t]) ? 0.0f : NEGINF;
        iA[t] = trigLast[t];
        iB[t] = fallLast[t];
    }
    __syncthreads();
    for (int d = 1; d < 256; d <<= 1) {
        float lA = NEGINF, lB = NEGINF; int lt_ = -1, lf_ = -1;
        bool act = t >= d;
        if (act) { lA = sA[t - d]; lB = sB[t - d]; lt_ = iA[t - d]; lf_ = iB[t - d]; }
        __syncthreads();
        if (act) {
            float nA = fmaxf(sA[t], sB[t] + lA);   // max-plus compose right∘left
            float nB = fmaxf(sB[t] + lB, NEGINF);
            sA[t] = nA; sB[t] = nB;
            iA[t] = max(iA[t], lt_);
            iB[t] = max(iB[t], lf_);
        }
        __syncthreads();
    }
    float inc_c; int trigIn_c, fallIn_c;
    if (c == 0) { inc_c = NEGINF; trigIn_c = -1; fallIn_c = -1; }
    else        { inc_c = sA[c - 1]; trigIn_c = iA[c - 1]; fallIn_c = iB[c - 1]; }
    __syncthreads();

    // ---------- Phase 3: finalize up_hat, local alpha affine scan ----------
    float uh = gate ? (open ? fmaxf(m_loc, inc_c) : m_loc) : u;
    out[3 * SEQ + i] = uh;   // up_hats
    out[2 * SEQ + i] = u;    // u_pred passthrough
    sA[t] = uh;
    sB[t] = (1.0f - uh) * a_i;
    __syncthreads();
    affine_scan256(sA, sB, t);
    float Pt = sA[t], Qt = sB[t];
    if (t == 255) { Pch[c] = Pt; Qch[c] = Qt; }
    grid_barrier(cnt, 2 * NCH, t);

    // ---------- Phase 4: alpha incoming, finalize alpha, local y affine scan ----------
    sA[t] = Pch[t]; sB[t] = Qch[t];
    __syncthreads();
    affine_scan256(sA, sB, t);
    float alphaIn_c = (c == 0) ? 0.0f : sB[c - 1];
    __syncthreads();
    float al = Pt * alphaIn_c + Qt;
    out[SEQ + i] = al;  // alphas
    sA[t] = gate ? (1.0f - al) : 0.0f;
    sB[t] = gate ? al * uh : 0.0f;
    __syncthreads();
    affine_scan256(sA, sB, t);
    float Et = sA[t], Ft = sB[t];
    if (t == 255) { Ech[c] = Et; Fch[c] = Ft; }
    grid_barrier(cnt, 3 * NCH, t);

    // ---------- Phase 5: y incoming, finalize y ----------
    sA[t] = Ech[t]; sB[t] = Fch[t];
    __syncthreads();
    affine_scan256(sA, sB, t);
    float yIn_c = (c == 0) ? 0.0f : sB[c - 1];
    float y_i = Et * yIn_c + Ft;
    out[i] = y_i;  // ys
    grid_barrier(cnt, 4 * NCH, t);

    // ---------- Phase 6: loss/cnt at gate falling edges ----------
    float contrib = 0.0f;
    int flag = 0;
    if (fall) {
        int j  = max(lt, trigIn_c);    // last label-trigger <= i
        int pf = max(lfE, fallIn_c);   // last fall < i
        float lc = 0.0f;
        if (j > pf) {
            bool gj = u_pred[j] >= THRES_UP;
            float d = out[j] - label[j];
            lc = gj ? d * d : -1.0f;
        }
        bool isneg = (lc == -1.0f);
        bool nonzero = (lc != 0.0f);
        if (!isneg) {
            if (nonzero) { contrib = lc; flag = 1; }   // * R, R = 1.0
            else {
                float ypre = out[i - 1];
                if (ypre >= THRES1) {
                    float t2 = thres2[(i < 59) ? i : 59];
                    float d2 = ypre - t2;
                    contrib = d2 * d2; flag = 1;
                }
            }
        }
    }
    #pragma unroll
    for (int off = 32; off; off >>= 1) {
        contrib += __shfl_down(contrib, off, 64);
        flag    += __shfl_down(flag, off, 64);
    }
    if ((t & 63) == 0 && (contrib != 0.0f || flag != 0)) {
        atomicAdd(&out[4 * SEQ], contrib);
        atomicAdd(&out[4 * SEQ + 1], (float)flag);
    }
}

extern "C" void kernel_launch(void* const* d_in, const int* in_sizes, int n_in,
                              void* d_out, int out_size, void* d_ws, size_t ws_size,
                              hipStream_t stream) {
    const float* h      = (const float*)d_in[0];
    const float* W      = (const float*)d_in[1];
    const float* b      = (const float*)d_in[2];
    const float* u_pred = (const float*)d_in[4];
    const float* label  = (const float*)d_in[5];
    const float* thres2 = (const float*)d_in[6];
    float* out  = (float*)d_out;
    float* base = (float*)d_ws;

    float* a   = base;                          // SEQ floats
    float* sf_ = base + SEQ;                    // 5*NCH floats
    int*   si_ = (int*)(base + SEQ + 5 * NCH);  // 4*NCH ints
    unsigned* cnt = (unsigned*)(si_ + 4 * NCH); // 1 counter

    k_matvec<<<SEQ / 4, 256, 0, stream>>>(h, W, b, a, cnt);

    void* args[] = { (void*)&u_pred, (void*)&label, (void*)&thres2, (void*)&a,
                     (void*)&out, (void*)&sf_, (void*)&si_, (void*)&cnt };
    hipLaunchCooperativeKernel((void*)k_scan, dim3(NCH), dim3(256), args, 0, stream);
}